// Round 9
// baseline (74.232 us; speedup 1.0000x reference)
//
#include <hip/hip_runtime.h>

typedef __attribute__((ext_vector_type(8)))  short short8;
typedef __attribute__((ext_vector_type(16))) float f32x16;
typedef unsigned int uint;

#define SEQ   2048
#define KB0   1024                 // x flat: u32 [0,1024); then 4 krev copies
#define KSTR  1048                 // copy stride (>=1040 needed); bases mod 32 = 0,24,16,8
#define ZB    (KB0 + 4 * KSTR)     // 5216: 32-u32 zero region (broadcast reads)
#define LDSU  (ZB + 32)            // 5248 u32 = 20992 B -> 7 blocks/CU (28 waves)
#define EXB   KB0                  // exchange region (reuse k-copies post-main): 4096 u32

__device__ inline uint pack2(float lo, float hi_) {
    uint ul = __float_as_uint(lo), uh = __float_as_uint(hi_);
    ul = (ul + 0x7fffu + ((ul >> 16) & 1u)) >> 16;   // RNE f32->bf16
    uh = (uh + 0x7fffu + ((uh >> 16) & 1u)) >> 16;
    return (ul & 0xffffu) | (uh << 16);
}

// XOR-swizzle on u32 index: bits 2-4 ^= bits 5-7 (bijective, b128-safe).
__device__ inline int swz(int v) { return v ^ ((v >> 3) & 28); }

#define MFMA(A, B, C) __builtin_amdgcn_mfma_f32_32x32x16_bf16( \
    __builtin_bit_cast(short8, A), __builtin_bit_cast(short8, B), C, 0, 0, 0)

// One 256-thread block (4 waves) per (b,d) row. Wave wv computes r = 8*wv .. 8*wv+7
// of Y(64x32) = sum_r shift_r(X) * T_r^T (32x32x16 bf16 MFMA). Two-phase LDS
// exchange reduces the 4 partials; wave (m=wv&1, h=wv>>1) stores tile m rows t=[8h,8h+8).
__global__ __launch_bounds__(256, 7)
void hyena_mfma(const float* __restrict__ x, const float* __restrict__ kern,
                const float* __restrict__ bias, float* __restrict__ out)
{
    __shared__ __align__(16) uint lds[LDSU];
    char* ldsb = (char*)lds;

    const int tid = threadIdx.x;       // 0..255
    const int wv  = tid >> 6;          // wave id 0..3
    const int l   = tid & 63;
    const int n   = l & 31;            // MFMA row (A) / col (B/D)
    const int hi  = l >> 5;            // k-group half
    const int row = blockIdx.x;        // b*2048 + d
    const size_t rb = (size_t)row * SEQ;
    const float bv = bias[row & 2047];

    // ---- stage x flat as bf16, swizzled (b128 writes, 8 elems/thread) ----
    {
        const int e = 8 * tid;                     // 0..2040 step 8
        float4 a = *(const float4*)&x[rb + e];
        float4 b = *(const float4*)&x[rb + e + 4];
        uint4 w = {pack2(a.x, a.y), pack2(a.z, a.w), pack2(b.x, b.y), pack2(b.z, b.w)};
        *(uint4*)&lds[swz(e >> 1)] = w;            // e>>1 mult of 4 -> b128-safe
    }
    // ---- stage 4 krev parity copies from registers ----
    // kr[i] = k[2047-i]; copy_c[m] = (kr[2m+c], kr[2m+c+1])
    {
        const int j = 8 * tid;                                // 0..2040 step 8
        const float* kp0 = &kern[rb + (j == 2040 ? 0 : (2036 - j))];
        const float* kp1 = &kern[rb + (2040 - j)];            // >= rb, 16B-aligned
        float4 f0 = *(const float4*)kp0;                      // (kr[j+11..j+8]) desc
        float4 f1 = *(const float4*)kp1;                      // (kr[j+7..j+4]) desc
        float4 f2 = *(const float4*)(kp1 + 4);                // (kr[j+3..j]) desc
        if (j == 2040) { f0.x = 0.f; f0.y = 0.f; f0.z = 0.f; f0.w = 0.f; }
        const float k0 = f2.w, k1 = f2.z, k2 = f2.y, k3 = f2.x;
        const float k4 = f1.w, k5 = f1.z, k6 = f1.y, k7 = f1.x;
        const float k8 = f0.w, k9 = f0.z, k10 = f0.y;
        const int m = j >> 1;                                 // mult of 4 -> 16B aligned
        uint4 w0 = {pack2(k0,k1), pack2(k2,k3), pack2(k4,k5), pack2(k6,k7)};
        uint4 w1 = {pack2(k1,k2), pack2(k3,k4), pack2(k5,k6), pack2(k7,k8)};
        uint4 w2 = {pack2(k2,k3), pack2(k4,k5), pack2(k6,k7), pack2(k8,k9)};
        uint4 w3 = {pack2(k3,k4), pack2(k5,k6), pack2(k7,k8), pack2(k9,k10)};
        *(uint4*)&lds[KB0 + m]            = w0;
        *(uint4*)&lds[KB0 + KSTR + m]     = w1;
        *(uint4*)&lds[KB0 + 2 * KSTR + m] = w2;
        *(uint4*)&lds[KB0 + 3 * KSTR + m] = w3;
    }
    if (tid < 16) {                    // copy tails (elements >= 2048 are zero)
        lds[KB0 + 1024 + tid]            = 0u;
        lds[KB0 + KSTR + 1024 + tid]     = 0u;
        lds[KB0 + 2 * KSTR + 1024 + tid] = 0u;
        lds[KB0 + 3 * KSTR + 1024 + tid] = 0u;
    }
    if (tid < 32) lds[ZB + tid] = 0u;  // shared zero region
    __syncthreads();

    // ---- per-lane bases (wave wv handles r = R0 .. R0+7) ----
    const int R0   = wv << 3;
    const int st00 = 2047 - n + 8 * hi;
    const int c    = st00 & 3;
    int kb = (KB0 + c * KSTR + ((st00 - c) >> 1)) * 4 - 2048 - (R0 << 6);
    int ua = 16 * n + 4 * hi - (R0 << 4);         // u32 idx, tile0 s0
    const int zb0 = ZB * 4 + 16 * hi;             // zero region (broadcast)

    f32x16 acc0 = {}, acc1a = {}, acc1b = {};

    #pragma unroll 2
    for (int i = 0; i < 8; ++i) {
        const int r = R0 + i;
        const int b0  = swz(ua) * 4;              // garbage if n<r (unselected)
        const int b0s = swz(ua + 8) * 4;
        const int b1  = swz(ua + 512) * 4;
        const int b1s = swz(ua + 520) * 4;
        const int va0  = (n >= r) ? b0  : zb0;
        const int va0s = (n >= r) ? b0s : (zb0 + 32);
        uint4 a00 = *(const uint4*)(ldsb + va0);             // A(-r,  s0)
        uint4 a01 = *(const uint4*)(ldsb + va0s);            // A(-r,  s1)
        uint4 a10 = *(const uint4*)(ldsb + b1);              // A(32-r,s0)
        uint4 a11 = *(const uint4*)(ldsb + b1s);             // A(32-r,s1)

        uint2 p0 = *(const uint2*)(ldsb + kb + 2048);        // T_r s0
        uint2 p1 = *(const uint2*)(ldsb + kb + 2056);
        uint2 p2 = *(const uint2*)(ldsb + kb + 2080);        // T_r s1
        uint2 p3 = *(const uint2*)(ldsb + kb + 2088);
        uint2 p4 = *(const uint2*)(ldsb + kb);               // T_{r+32} s0
        uint2 p5 = *(const uint2*)(ldsb + kb + 8);
        uint2 p6 = *(const uint2*)(ldsb + kb + 32);          // T_{r+32} s1
        uint2 p7 = *(const uint2*)(ldsb + kb + 40);
        uint4 b00 = {p0.x, p0.y, p1.x, p1.y};
        uint4 b01 = {p2.x, p2.y, p3.x, p3.y};
        uint4 b10 = {p4.x, p4.y, p5.x, p5.y};
        uint4 b11 = {p6.x, p6.y, p7.x, p7.y};

        acc0  = MFMA(a00, b00, acc0);    // tile0 += X(-r)   * T_r^T
        acc1a = MFMA(a10, b00, acc1a);   // tile1 += X(32-r) * T_r^T
        acc0  = MFMA(a01, b01, acc0);
        acc1a = MFMA(a11, b01, acc1a);
        acc1b = MFMA(a00, b10, acc1b);   // tile1 += X(-r)   * T_{r+32}^T
        acc1b = MFMA(a01, b11, acc1b);

        ua -= 16;        // shift: -32 x elements
        kb -= 64;        // shift: -32 krev elements = -16 u32
    }
    const f32x16 acc1 = acc1a + acc1b;
    __syncthreads();     // all k reads done before exchange overwrites copies

    // ---- two-phase exchange; owner (m=wv&1, h=wv>>1) sums & stores 8 rows ----
    // layout: idx(h, w, q2) = EXB + (((h*4 + w)*2 + q2)*64 + l)*4  (lane-contiguous f4)
    const int m_own = wv & 1, h_own = wv >> 1;
    float s[8];
    #pragma unroll
    for (int ph = 0; ph < 2; ++ph) {               // ph = tile being reduced
        const f32x16& a = ph ? acc1 : acc0;
        #pragma unroll
        for (int h = 0; h < 2; ++h)
            #pragma unroll
            for (int q2 = 0; q2 < 2; ++q2) {
                float4 f = {a[8*h+4*q2], a[8*h+4*q2+1], a[8*h+4*q2+2], a[8*h+4*q2+3]};
                *(float4*)&lds[EXB + (((h * 4 + wv) * 2 + q2) * 64 + l) * 4] = f;
            }
        __syncthreads();
        if (m_own == ph) {
            #pragma unroll
            for (int j = 0; j < 8; ++j) s[j] = a[8 * h_own + j];
            #pragma unroll
            for (int w = 0; w < 4; ++w) {
                if (w == wv) continue;
                #pragma unroll
                for (int q2 = 0; q2 < 2; ++q2) {
                    float4 f = *(const float4*)&lds[EXB + (((h_own*4 + w)*2 + q2)*64 + l)*4];
                    s[4*q2]   += f.x; s[4*q2+1] += f.y;
                    s[4*q2+2] += f.z; s[4*q2+3] += f.w;
                }
            }
        }
        __syncthreads();                            // reads done before next phase write
    }

    // ---- store: 8 rows of tile m_own; residual x from LDS bf16 ----
    #pragma unroll
    for (int t8 = 0; t8 < 8; ++t8) {
        const int t = 8 * h_own + t8;
        const int rloc = (t & 3) + 8 * (t >> 2) + 4 * hi;   // verified 32x32 C/D map
        const int p = 32 * m_own + rloc;
        const uint w = lds[swz(16 * p + (n >> 1))];
        const float xr = __uint_as_float((n & 1) ? (w & 0xffff0000u) : (w << 16));
        out[rb + (size_t)p * 32 + n] = s[t8] + xr + bv;
    }
}

extern "C" void kernel_launch(void* const* d_in, const int* in_sizes, int n_in,
                              void* d_out, int out_size, void* d_ws, size_t ws_size,
                              hipStream_t stream) {
    const float* x    = (const float*)d_in[0];   // (4, 2048, 2048) f32
    const float* kern = (const float*)d_in[1];   // (4, 2048, 2048) f32
    const float* bias = (const float*)d_in[2];   // (2048,) f32
    float* out = (float*)d_out;                  // (4, 2048, 2048) f32

    hipLaunchKernelGGL(hyena_mfma, dim3(4 * 2048), dim3(256), 0, stream,
                       x, kern, bias, out);
}

// Round 10
// 60.496 us; speedup vs baseline: 1.2271x; 1.2271x over previous
//
#include <hip/hip_runtime.h>

typedef __attribute__((ext_vector_type(8)))  short short8;
typedef __attribute__((ext_vector_type(16))) float f32x16;
typedef unsigned int uint;

#define SEQ   2048
#define KB0   1024                 // x flat bf16: u32 [0,1024); then 2 krev parity copies
#define KSTR2 1040                 // u32 per copy (reads reach m=1038)
#define KB1   (KB0 + KSTR2)        // 2064: odd-parity copy
#define ZB    (KB0 + 2 * KSTR2)    // 3104: 16-u32 zero region (broadcast reads)
#define LDSU  (ZB + 16)            // 3120 u32 = 12480 B -> 13 blocks/CU (26 waves)
#define EX0   1024                 // exchange regions (reuse k copies post-main)
#define EX1   2048                 // 1024 u32 each, [q][lane] f4 layout

__device__ inline uint pack2(float lo, float hi_) {
    uint ul = __float_as_uint(lo), uh = __float_as_uint(hi_);
    ul = (ul + 0x7fffu + ((ul >> 16) & 1u)) >> 16;   // RNE f32->bf16
    uh = (uh + 0x7fffu + ((uh >> 16) & 1u)) >> 16;
    return (ul & 0xffffu) | (uh << 16);
}

// XOR-swizzle on u32 index: bits 2-4 ^= bits 5-7 (bijective, b128-safe).
__device__ inline int swz(int v) { return v ^ ((v >> 3) & 28); }

#define MFMA(A, B, C) __builtin_amdgcn_mfma_f32_32x32x16_bf16( \
    __builtin_bit_cast(short8, A), __builtin_bit_cast(short8, B), C, 0, 0, 0)

// One 128-thread block (2 waves) per (b,d) row. Wave wv computes r = 16*wv..16*wv+15
// of Y(64x32) = sum_r shift_r(X) * T_r^T (32x32x16 bf16 MFMA); waves exchange partial
// accumulators through LDS, each writes one 32-row output tile.
// B-frags: 4 consecutive u32 at ARBITRARY u32 index in a parity-matched krev copy
// -> pairs of adjacent ds_read_b32 merge to ds_read2_b32 (alignment-free).
__global__ __launch_bounds__(128, 6)
void hyena_mfma(const float* __restrict__ x, const float* __restrict__ kern,
                const float* __restrict__ bias, float* __restrict__ out)
{
    __shared__ __align__(16) uint lds[LDSU];
    char* ldsb = (char*)lds;

    const int tid = threadIdx.x;       // 0..127
    const int wv  = tid >> 6;          // wave id 0,1
    const int l   = tid & 63;
    const int n   = l & 31;            // MFMA row (A) / col (B/D)
    const int hi  = l >> 5;            // k-group half
    const int row = blockIdx.x;        // b*2048 + d
    const size_t rb = (size_t)row * SEQ;
    const float bv = bias[row & 2047];

    // ---- stage x flat as bf16, swizzled (b128 writes, 8 elems/thread) ----
    #pragma unroll
    for (int it = 0; it < 2; ++it) {
        const int e = it * 1024 + 8 * tid;         // 0..2040 step 8
        float4 a = *(const float4*)&x[rb + e];
        float4 b = *(const float4*)&x[rb + e + 4];
        uint4 w = {pack2(a.x, a.y), pack2(a.z, a.w), pack2(b.x, b.y), pack2(b.z, b.w)};
        *(uint4*)&lds[swz(e >> 1)] = w;            // e>>1 mult of 4 -> b128-safe
    }
    // ---- stage 2 krev parity copies: cpE[m]=(kr[2m],kr[2m+1]), cpO[m]=(kr[2m+1],kr[2m+2])
    #pragma unroll
    for (int it = 0; it < 2; ++it) {
        const int j = it * 1024 + 8 * tid;                    // 0..2040 step 8
        const float* kp0 = &kern[rb + (j == 2040 ? 0 : (2036 - j))];
        const float* kp1 = &kern[rb + (2040 - j)];            // >= rb, 16B-aligned
        float4 f0 = *(const float4*)kp0;                      // (kr[j+11..j+8]) desc
        float4 f1 = *(const float4*)kp1;                      // (kr[j+7..j+4]) desc
        float4 f2 = *(const float4*)(kp1 + 4);                // (kr[j+3..j]) desc
        if (j == 2040) { f0.x = 0.f; f0.y = 0.f; f0.z = 0.f; f0.w = 0.f; }
        const float k0 = f2.w, k1 = f2.z, k2 = f2.y, k3 = f2.x;
        const float k4 = f1.w, k5 = f1.z, k6 = f1.y, k7 = f1.x;
        const float k8 = f0.w;
        const int m = j >> 1;                                 // mult of 4 -> 16B aligned
        uint4 w0 = {pack2(k0,k1), pack2(k2,k3), pack2(k4,k5), pack2(k6,k7)};
        uint4 w1 = {pack2(k1,k2), pack2(k3,k4), pack2(k5,k6), pack2(k7,k8)};
        *(uint4*)&lds[KB0 + m] = w0;
        *(uint4*)&lds[KB1 + m] = w1;
    }
    if (tid < 16) {                    // copy tails (elements >= 2048 are zero) + zeros
        lds[KB0 + 1024 + tid] = 0u;
        lds[KB1 + 1024 + tid] = 0u;
        lds[ZB + tid] = 0u;
    }
    __syncthreads();

    // ---- per-lane bases (wave wv handles r = R0 .. R0+15) ----
    const int R0   = wv << 4;
    const int st00 = 2047 - n + 8 * hi;
    const int par  = st00 & 1;
    int kb  = (KB0 + par * KSTR2 + (st00 >> 1)) * 4 - 2048 - (R0 << 6);  // T_{r+32} base
    int kbh = kb + 2048;                                                 // T_r base
    asm volatile("" : "+v"(kbh));   // opaque: keep independent DS base so adjacent
                                    // b32 reads merge to ds_read2_b32 (small offsets)
    int ua = 16 * n + 4 * hi - (R0 << 4);         // u32 idx, tile0 s0
    const int zb0 = ZB * 4 + 16 * hi;             // zero region (broadcast)

    f32x16 acc0 = {}, acc1a = {}, acc1b = {};

    #pragma unroll 2
    for (int i = 0; i < 16; ++i) {
        const int r = R0 + i;
        const int b0  = swz(ua) * 4;              // garbage if n<r (unselected)
        const int b0s = swz(ua + 8) * 4;
        const int b1  = swz(ua + 512) * 4;
        const int b1s = swz(ua + 520) * 4;
        const int va0  = (n >= r) ? b0  : zb0;
        const int va0s = (n >= r) ? b0s : (zb0 + 32);
        uint4 a00 = *(const uint4*)(ldsb + va0);             // A(-r,  s0)
        uint4 a01 = *(const uint4*)(ldsb + va0s);            // A(-r,  s1)
        uint4 a10 = *(const uint4*)(ldsb + b1);              // A(32-r,s0)
        uint4 a11 = *(const uint4*)(ldsb + b1s);             // A(32-r,s1)

        const uint* kl = (const uint*)(ldsb + kb);           // T_{r+32}
        const uint* kh = (const uint*)(ldsb + kbh);          // T_r
        uint4 b00 = {kh[0], kh[1], kh[2],  kh[3]};           // s0
        uint4 b01 = {kh[8], kh[9], kh[10], kh[11]};          // s1
        uint4 b10 = {kl[0], kl[1], kl[2],  kl[3]};           // s0
        uint4 b11 = {kl[8], kl[9], kl[10], kl[11]};          // s1

        acc0  = MFMA(a00, b00, acc0);    // tile0 += X(-r)   * T_r^T
        acc1a = MFMA(a10, b00, acc1a);   // tile1 += X(32-r) * T_r^T
        acc0  = MFMA(a01, b01, acc0);
        acc1a = MFMA(a11, b01, acc1a);
        acc1b = MFMA(a00, b10, acc1b);   // tile1 += X(-r)   * T_{r+32}^T
        acc1b = MFMA(a01, b11, acc1b);

        ua  -= 16;       // shift: -32 x elements
        kb  -= 64;       // shift: -32 krev elements = -16 u32
        kbh -= 64;
    }
    __syncthreads();     // all k reads done before exchange overwrites copies

    // ---- cross-wave partial exchange: [q][lane] f4 layout (even 8-lane/bank) ----
    f32x16 part_send, part_keep;
    if (wv == 0) { part_send = acc1a + acc1b; part_keep = acc0; }
    else         { part_send = acc0;          part_keep = acc1a + acc1b; }
    const int exw = (wv == 0) ? EX0 : EX1;
    const int exr = (wv == 0) ? EX1 : EX0;
    #pragma unroll
    for (int q = 0; q < 4; ++q) {
        float4 f = {part_send[4*q], part_send[4*q+1], part_send[4*q+2], part_send[4*q+3]};
        *(float4*)&lds[exw + q * 256 + 4 * l] = f;
    }
    __syncthreads();
    f32x16 tile = part_keep;
    #pragma unroll
    for (int q = 0; q < 4; ++q) {
        float4 f = *(const float4*)&lds[exr + q * 256 + 4 * l];
        tile[4*q] += f.x; tile[4*q+1] += f.y; tile[4*q+2] += f.z; tile[4*q+3] += f.w;
    }

    // ---- epilogue: wave wv writes tile wv; y = acc + x(bf16 from LDS) + bias ----
    #pragma unroll
    for (int t = 0; t < 16; ++t) {
        const int rloc = (t & 3) + 8 * (t >> 2) + 4 * hi;  // verified 32x32 C/D map
        const int p = 32 * wv + rloc;
        const uint w = lds[swz(16 * p + (n >> 1))];
        const float xr = __uint_as_float((n & 1) ? (w & 0xffff0000u) : (w << 16));
        out[rb + (size_t)p * 32 + n] = tile[t] + xr + bv;
    }
}

extern "C" void kernel_launch(void* const* d_in, const int* in_sizes, int n_in,
                              void* d_out, int out_size, void* d_ws, size_t ws_size,
                              hipStream_t stream) {
    const float* x    = (const float*)d_in[0];   // (4, 2048, 2048) f32
    const float* kern = (const float*)d_in[1];   // (4, 2048, 2048) f32
    const float* bias = (const float*)d_in[2];   // (2048,) f32
    float* out = (float*)d_out;                  // (4, 2048, 2048) f32

    hipLaunchKernelGGL(hyena_mfma, dim3(4 * 2048), dim3(128), 0, stream,
                       x, kern, bias, out);
}